// Round 7
// baseline (170.473 us; speedup 1.0000x reference)
//
#include <hip/hip_runtime.h>
#include <hip/hip_bf16.h>
#include <math.h>

// Problem constants (fixed by reference setup_inputs)
#define BN 8192       // batch
#define DK 256        // embedding dim (= GEMM K)
#define TM 128        // row/col tile
#define NP 41         // partial planes: 9 row-slots (dgroup) + 32 col-slots (d=1..32)
#define INV_T 1.42857142857142857f   // 1/0.7
#define C2E   2.060992915555662f     // log2(e)/0.7  (for exp2-based exp)

using bf16x8 = __attribute__((ext_vector_type(8))) short;  // 8 bf16 = 4 VGPRs
using f32x4  = __attribute__((ext_vector_type(4))) float;

__device__ __forceinline__ void async_copy16(void* lds, const void* g) {
  __builtin_amdgcn_global_load_lds(
      (const __attribute__((address_space(1))) unsigned int*)g,
      (__attribute__((address_space(3))) unsigned int*)lds,
      16, 0, 0);
}

// ---------------- Kernel 1: L2-normalize rows, fp32 -> bf16 ----------------
// One wave per row: float4 loads, shuffle reduce, ushort4 stores. No LDS.
// Also initializes the partial planes (plane-major [NP][BN]) and zeroes the
// 3-word accumulator (loss, count, ticket) so no hipMemset node is needed.
__global__ void norm_kernel(const float* __restrict__ E, unsigned short* __restrict__ Eb,
                            float* __restrict__ posPart, float* __restrict__ negPart,
                            float* __restrict__ accum) {
  const int gid = blockIdx.x * 256 + threadIdx.x;   // 2048*256 = 524288 threads
  if (gid < NP * BN) {                               // 335872 < 524288
    posPart[gid] = -1e30f;
    negPart[gid] = 0.0f;
  }
  if (blockIdx.x == 0 && threadIdx.x < 3) accum[threadIdx.x] = 0.0f;  // bits 0 == uint 0
  const int wv = threadIdx.x >> 6, lane = threadIdx.x & 63;
  const int row = blockIdx.x * 4 + wv;
  const float4 x = *(const float4*)&E[(size_t)row * DK + lane * 4];
  float ss = x.x * x.x + x.y * x.y + x.z * x.z + x.w * x.w;
#pragma unroll
  for (int m = 1; m < 64; m <<= 1) ss += __shfl_xor(ss, m);
  const float scale = 1.0f / fmaxf(sqrtf(ss), 1e-12f);
  ushort4 o;
  __hip_bfloat16 h0 = __float2bfloat16(x.x * scale); o.x = *(unsigned short*)&h0;
  __hip_bfloat16 h1 = __float2bfloat16(x.y * scale); o.y = *(unsigned short*)&h1;
  __hip_bfloat16 h2 = __float2bfloat16(x.z * scale); o.z = *(unsigned short*)&h2;
  __hip_bfloat16 h3 = __float2bfloat16(x.w * scale); o.w = *(unsigned short*)&h3;
  *(ushort4*)&Eb[(size_t)row * DK + lane * 4] = o;
}

// ---------------- Kernel 2: fused sims + masked max / sum-exp ----------------
// SYMMETRIC-HALVED tile set (each unordered 128x128 block-pair once):
// (I, (I+d)&63) for d=0..31 all I, plus d=32 for I<32 -> 2080 tiles.
// Block = (I, dgroup): dg<8 -> d=4dg..4dg+3; dg==8 (I<32, mapped to
// blockIdx.y==0 so they dispatch first) -> d=32.
//
// STRUCTURE = round-1's proven loop: A panel (64 KB) persistent; Bs single
// BK=64 buffer (16 KB); per kc: {sync; stage(4/thr); sync; 2 K32-slices x
// 16 MFMA}. LDS mapping is the chunk-contiguous layout (r3/r5/r6-proven,
// SQ_LDS_BANK_CONFLICT = 0): As/Bs hold [panel][k-slot][c16] 16B chunks so
// every ds_read_b128 reads 1024 CONTIGUOUS bytes; staging keeps full
// 64B-sector coalescing (4 lanes per 64B line).
//
// LAUNCH BOUNDS: max-threads ONLY. r2-r6 all pinned VGPR_Count at exactly
// 128 and spilled into the k-loop (WRITE_SIZE 11.8-73.9 MB vs the 2.6 MB of
// real output): __launch_bounds__(256,2)'s occupancy target made the backend
// cap arch-VGPRs at 128. The cap buys nothing: LDS (80 KB) already limits
// occupancy to 2 blocks/CU = 2 waves/SIMD, which is sustainable for any
// VGPR count <= 256. Let the allocator take ~150-200 regs, spill-free.
// Partials: plane-major [NP][BN]; plane = dg (row stats) or 8+d (col stats).
__launch_bounds__(256)
__global__ void contrast_kernel(const unsigned short* __restrict__ Eb,
                                const int* __restrict__ cat,
                                float* __restrict__ posPart,
                                float* __restrict__ negPart) {
  // As chunk layout: idx = (rh*8 + ks)*64 + q*16 + c16   (ks = K32 slice 0..7)
  //   holds global A[row = rh*16 + c16][k = ks*32 + q*8 .. +8]
  __shared__ __align__(16) unsigned short As[TM * DK];   // 64 KB
  // Bs chunk layout: idx = ((colhi*2 + s)*4 + q)*16 + c16   (s = K32 within K64)
  //   holds global B[col = colhi*16 + c16][k = kc*64 + s*32 + q*8 .. +8]
  __shared__ __align__(16) unsigned short Bs[TM * 64];   // 16 KB

  const int tid = threadIdx.x;
  const int lane = tid & 63;
  const int wv = tid >> 6;
  const int wm = wv >> 1;      // wave row (0..1)
  const int wn = wv & 1;       // wave col (0..1)
  const int quad = lane >> 4;
  const int l16 = lane & 15;

  const int I = blockIdx.x;
  const int dg = (blockIdx.y == 0) ? 8 : (int)blockIdx.y - 1;  // light blocks first
  if (dg == 8 && I >= 32) return;      // d=32 tiles exist only for I<32
  const int ntiles = (dg == 8) ? 1 : 4;
  const int rowBase = I * TM;

  // ---- stage A panel: 64 KB, chunk layout, 16 copies/thread ----
  {
    const char* gbase = (const char*)(Eb + (size_t)rowBase * DK);
#pragma unroll
    for (int i = 0; i < 16; ++i) {
      const int idx = tid + i * 256;       // 4096 chunks of 16B
      const int rhks = idx >> 6;           // rh = rhks>>3, ks = rhks&7
      const int q = (idx >> 4) & 3, c16 = idx & 15;
      async_copy16((char*)As + idx * 16,
                   gbase + ((rhks >> 3) * 16 + c16) * 512 +
                       ((rhks & 7) * 4 + q) * 16);
    }
  }

  // Rows owned by this lane (C layout: col=lane&15, row=quad*4+reg):
  int catRow[16];
  float posmx[16], negsm[16];
#pragma unroll
  for (int ti = 0; ti < 4; ++ti)
#pragma unroll
    for (int r = 0; r < 4; ++r) {
      const int si = ti * 4 + r;
      catRow[si] = cat[rowBase + wm * 64 + ti * 16 + quad * 4 + r];
      posmx[si] = -1e30f;
      negsm[si] = 0.0f;
    }

#pragma unroll 1
  for (int t = 0; t < ntiles; ++t) {
    const int d = (dg == 8) ? 32 : dg * 4 + t;   // block-distance of this tile
    const int colBase = ((I + d) & 63) * TM;

    f32x4 acc[4][4];
#pragma unroll
    for (int ti = 0; ti < 4; ++ti)
#pragma unroll
      for (int tj = 0; tj < 4; ++tj)
        acc[ti][tj] = f32x4{0.f, 0.f, 0.f, 0.f};

#pragma unroll 1
    for (int kc = 0; kc < 4; ++kc) {
      __syncthreads();  // prev Bs consumers done (t=0,kc=0: covers nothing yet)
      {
        // stage BK=64 B chunk (16 KB, 4 copies/thread), chunk layout
#pragma unroll
        for (int it = 0; it < 4; ++it) {
          const int idx = tid + it * 256;    // 1024 chunks of 16B
          const int c16 = idx & 15, q = (idx >> 4) & 3;
          const int s = (idx >> 6) & 1, colhi = idx >> 7;
          async_copy16((char*)Bs + idx * 16,
                       (const char*)Eb +
                           (size_t)(colBase + colhi * 16 + c16) * 512 +
                           kc * 128 + s * 64 + q * 16);
        }
      }
      __syncthreads();  // Bs ready (barrier drains vmcnt; t=0,kc=0: A too)

#pragma unroll
      for (int s = 0; s < 2; ++s) {
        bf16x8 a[4], b[4];
#pragma unroll
        for (int ti = 0; ti < 4; ++ti)
          a[ti] = *(const bf16x8*)((const char*)As +
                  ((((wm * 4 + ti) * 8 + (kc * 2 + s)) * 64 +
                    quad * 16 + l16) * 16));
#pragma unroll
        for (int tj = 0; tj < 4; ++tj)
          b[tj] = *(const bf16x8*)((const char*)Bs +
                  (((((wn * 4 + tj) * 2 + s) * 4 + quad) * 16 + l16) * 16));
#pragma unroll
        for (int ti = 0; ti < 4; ++ti)
#pragma unroll
          for (int tj = 0; tj < 4; ++tj)
            acc[ti][tj] = __builtin_amdgcn_mfma_f32_16x16x32_bf16(
                a[ti], b[tj], acc[ti][tj], 0, 0, 0);
      }
    }

    // ---- fused epilogue for this 128x128 tile (acc = raw cosines) ----
    int catCol[4];
#pragma unroll
    for (int tj = 0; tj < 4; ++tj) catCol[tj] = cat[colBase + wn * 64 + tj * 16 + l16];

    if (d == 0) {
      // diagonal tile: row stats only; self-exclusion needed; no col stats
#pragma unroll
      for (int ti = 0; ti < 4; ++ti)
#pragma unroll
        for (int r = 0; r < 4; ++r) {
          const int si = ti * 4 + r;
          const int rl = wm * 64 + ti * 16 + quad * 4 + r;   // local row
          float pm = posmx[si];
          float ns = negsm[si];
#pragma unroll
          for (int tj = 0; tj < 4; ++tj) {
            const float v = acc[ti][tj][r];
            const bool same = (catRow[si] == catCol[tj]);
            const bool self = (rl == wn * 64 + tj * 16 + l16);
            const float e = exp2f(__fmaf_rn(v, C2E, -C2E));
            ns += same ? 0.0f : e;
            pm = (same && !self) ? fmaxf(pm, v) : pm;
          }
          posmx[si] = pm;
          negsm[si] = ns;
        }
    } else {
      // off-diagonal: row stats + column stats (no self possible, I != J)
      float cp[4], cn[4];
#pragma unroll
      for (int tj = 0; tj < 4; ++tj) { cp[tj] = -1e30f; cn[tj] = 0.0f; }
#pragma unroll
      for (int ti = 0; ti < 4; ++ti)
#pragma unroll
        for (int r = 0; r < 4; ++r) {
          const int si = ti * 4 + r;
          float pm = posmx[si];
          float ns = negsm[si];
#pragma unroll
          for (int tj = 0; tj < 4; ++tj) {
            const float v = acc[ti][tj][r];
            const bool same = (catRow[si] == catCol[tj]);
            const float e = exp2f(__fmaf_rn(v, C2E, -C2E));
            const float en = same ? 0.0f : e;
            ns += en;
            cn[tj] += en;
            pm = same ? fmaxf(pm, v) : pm;
            cp[tj] = same ? fmaxf(cp[tj], v) : cp[tj];
          }
          posmx[si] = pm;
          negsm[si] = ns;
        }

      // column-stat reduce: quads via shuffle, wm halves via Bs scratch
#pragma unroll
      for (int tj = 0; tj < 4; ++tj) {
        cp[tj] = fmaxf(cp[tj], __shfl_xor(cp[tj], 16));
        cp[tj] = fmaxf(cp[tj], __shfl_xor(cp[tj], 32));
        cn[tj] += __shfl_xor(cn[tj], 16);
        cn[tj] += __shfl_xor(cn[tj], 32);
      }
      float* sred = (float*)Bs;
      __syncthreads();           // all waves done reading Bs for MFMA
      if (wm == 1 && quad == 0) {
#pragma unroll
        for (int tj = 0; tj < 4; ++tj) {
          sred[wn * 64 + tj * 16 + l16] = cp[tj];
          sred[128 + wn * 64 + tj * 16 + l16] = cn[tj];
        }
      }
      __syncthreads();           // scratch visible
      if (wm == 0 && quad == 0) {
#pragma unroll
        for (int tj = 0; tj < 4; ++tj) {
          const int C = colBase + wn * 64 + tj * 16 + l16;   // coalesced over l16
          posPart[(size_t)(8 + d) * BN + C] = fmaxf(cp[tj], sred[wn * 64 + tj * 16 + l16]);
          negPart[(size_t)(8 + d) * BN + C] = cn[tj] + sred[128 + wn * 64 + tj * 16 + l16];
        }
      }
      // next tile's kc=0 first sync protects sred reads before restaging Bs
    }
  }

  // ---- row stats: reduce across the 16 lanes sharing each row (cols split) ----
#pragma unroll
  for (int si = 0; si < 16; ++si) {
    float pm = posmx[si], ns = negsm[si];
#pragma unroll
    for (int m = 1; m < 16; m <<= 1) {
      pm = fmaxf(pm, __shfl_xor(pm, m));
      ns += __shfl_xor(ns, m);
    }
    posmx[si] = pm;
    negsm[si] = ns;
  }

  // ---- combine the wn=0 / wn=1 wave halves via LDS (reuse As) ----
  float* red = (float*)As;  // [0..127]=pos, [128..255]=neg
  __syncthreads();
  if (wn == 1 && l16 == 0) {
#pragma unroll
    for (int si = 0; si < 16; ++si) {
      const int rl = wm * 64 + (si >> 2) * 16 + quad * 4 + (si & 3);
      red[rl] = posmx[si];
      red[128 + rl] = negsm[si];
    }
  }
  __syncthreads();
  if (wn == 0 && l16 == 0) {
#pragma unroll
    for (int si = 0; si < 16; ++si) {
      const int rl = wm * 64 + (si >> 2) * 16 + quad * 4 + (si & 3);
      const float pm = fmaxf(posmx[si], red[rl]);
      const float ns = negsm[si] + red[128 + rl];
      posPart[(size_t)dg * BN + rowBase + rl] = pm;  // raw cosine max
      negPart[(size_t)dg * BN + rowBase + rl] = ns;
    }
  }
}

// ---------------- Kernel 3: per-row loss, accumulate, final division ----------------
// 32 blocks x 256: one thread per row; plane-major partials -> each of the NP
// reads is a fully-coalesced 256-thread load. Last block (atomic ticket)
// performs the division -- no separate epilogue kernel, no memset node.
__global__ void finalize_kernel(const float* __restrict__ posPart,
                                const float* __restrict__ negPart,
                                float* __restrict__ accum,
                                float* __restrict__ out) {
  const int tid = threadIdx.x;
  const int row = blockIdx.x * 256 + tid;
  float pm = -1e30f, ns = 0.0f;
#pragma unroll
  for (int g = 0; g < NP; ++g) {
    pm = fmaxf(pm, posPart[(size_t)g * BN + row]);
    ns += negPart[(size_t)g * BN + row];
  }
  float loss = 0.0f, c = 0.0f;
  if (pm > -1e29f && ns > 0.0f) {   // valid: has positive AND negative
    const float pos = pm * INV_T;
    const float lse = INV_T + logf(expf(pos - INV_T) + ns);
    loss = lse - pos;
    c = 1.0f;
  }
#pragma unroll
  for (int m = 1; m < 64; m <<= 1) {
    loss += __shfl_xor(loss, m);
    c += __shfl_xor(c, m);
  }
  __shared__ float sL[4], sC[4];
  const int wv = tid >> 6, lane = tid & 63;
  if (lane == 0) { sL[wv] = loss; sC[wv] = c; }
  __syncthreads();
  if (tid == 0) {
    atomicAdd(&accum[0], sL[0] + sL[1] + sL[2] + sL[3]);
    atomicAdd(&accum[1], sC[0] + sC[1] + sC[2] + sC[3]);
    __threadfence();
    const unsigned old = atomicAdd((unsigned*)&accum[2], 1u);
    if (old == 31u) {            // last block: totals are visible (fence+ticket)
      const float L = atomicAdd(&accum[0], 0.0f);
      const float C = atomicAdd(&accum[1], 0.0f);
      out[0] = (C > 0.0f) ? L / C : 0.0f;
    }
  }
}

extern "C" void kernel_launch(void* const* d_in, const int* in_sizes, int n_in,
                              void* d_out, int out_size, void* d_ws, size_t ws_size,
                              hipStream_t stream) {
  const float* E = (const float*)d_in[0];
  const int* cat = (const int*)d_in[1];
  // d_in[2] (font_labels) unused by the reference.

  // Workspace: [0,4MB) bf16 normalized embeddings; [NP][BN] partials x2; 12B accum.
  unsigned short* Eb = (unsigned short*)d_ws;
  float* posPart = (float*)((char*)d_ws + (size_t)BN * DK * 2);
  float* negPart = posPart + (size_t)NP * BN;
  float* accum = negPart + (size_t)NP * BN;
  float* out = (float*)d_out;

  hipLaunchKernelGGL(norm_kernel, dim3(BN / 4), dim3(256), 0, stream,
                     E, Eb, posPart, negPart, accum);
  hipLaunchKernelGGL(contrast_kernel, dim3(BN / TM, 9), dim3(256), 0, stream,
                     Eb, cat, posPart, negPart);
  hipLaunchKernelGGL(finalize_kernel, dim3(BN / 256), dim3(256), 0, stream,
                     posPart, negPart, accum, out);
}

// Round 8
// 143.051 us; speedup vs baseline: 1.1917x; 1.1917x over previous
//
#include <hip/hip_runtime.h>
#include <hip/hip_bf16.h>
#include <math.h>

// Problem constants (fixed by reference setup_inputs)
#define BN 8192       // batch
#define DK 256        // embedding dim (= GEMM K)
#define TM 128        // row/col tile
#define NP 41         // partial planes: 9 row-slots (dgroup) + 32 col-slots (d=1..32)
#define INV_T 1.42857142857142857f   // 1/0.7
#define C2E   2.060992915555662f     // log2(e)/0.7  (for exp2-based exp)

using bf16x8 = __attribute__((ext_vector_type(8))) short;  // 8 bf16 = 4 VGPRs
using f32x4  = __attribute__((ext_vector_type(4))) float;

__device__ __forceinline__ void async_copy16(void* lds, const void* g) {
  __builtin_amdgcn_global_load_lds(
      (const __attribute__((address_space(1))) unsigned int*)g,
      (__attribute__((address_space(3))) unsigned int*)lds,
      16, 0, 0);
}

// ---------------- Kernel 1: L2-normalize rows, fp32 -> bf16 ----------------
// One wave per row: float4 loads, shuffle reduce, ushort4 stores. No LDS.
// Zeroes the 3-word accumulator (loss, count, ticket) -> no memset node.
// NO partial-plane init: finalize reads only written cells (plane 8 valid
// for rows<4096, plane 40 for rows>=4096, all others fully written).
__global__ void norm_kernel(const float* __restrict__ E, unsigned short* __restrict__ Eb,
                            float* __restrict__ accum) {
  if (blockIdx.x == 0 && threadIdx.x < 3) accum[threadIdx.x] = 0.0f;  // bits 0 == uint 0
  const int wv = threadIdx.x >> 6, lane = threadIdx.x & 63;
  const int row = blockIdx.x * 4 + wv;
  const float4 x = *(const float4*)&E[(size_t)row * DK + lane * 4];
  float ss = x.x * x.x + x.y * x.y + x.z * x.z + x.w * x.w;
#pragma unroll
  for (int m = 1; m < 64; m <<= 1) ss += __shfl_xor(ss, m);
  const float scale = 1.0f / fmaxf(sqrtf(ss), 1e-12f);
  ushort4 o;
  __hip_bfloat16 h0 = __float2bfloat16(x.x * scale); o.x = *(unsigned short*)&h0;
  __hip_bfloat16 h1 = __float2bfloat16(x.y * scale); o.y = *(unsigned short*)&h1;
  __hip_bfloat16 h2 = __float2bfloat16(x.z * scale); o.z = *(unsigned short*)&h2;
  __hip_bfloat16 h3 = __float2bfloat16(x.w * scale); o.w = *(unsigned short*)&h3;
  *(ushort4*)&Eb[(size_t)row * DK + lane * 4] = o;
}

// ---------------- Kernel 2: fused sims + masked max / sum-exp ----------------
// SYMMETRIC-HALVED tile set (each unordered 128x128 block-pair once):
// (I, (I+d)&63) for d=0..31 all I, plus d=32 for I<32 -> 2080 tiles.
// Block = (I, dgroup): dg<8 -> d=4dg..4dg+3; dg==8 (I<32, mapped to
// blockIdx.y==0 so they dispatch first) -> d=32.
//
// REVERT-TO-PROVEN: this is the 49.0 us kernel (round-1 measurement)
// byte-identical in its staging + k-loop + LDS XOR-swizzle + launch bounds
// (256,2) -> 116 VGPR, spill-free. Six structural variants (B-in-reg,
// chunk layouts, ping-pong pipelines, unbounded VGPR) all measured slower
// (65-93 us) via spill or occupancy loss. Only the proven-bit-exact
// epilogue split (diag vs off-diag, exp2f, no rowIdx/colIdx arrays ->
// LESS register pressure than the original 116) is kept from r2-r7.
// LDS = 64 KB As + 16 KB Bs = 80 KB -> 2 blocks/CU.
// Partials: plane-major [NP][BN]; plane = dg (row stats) or 8+d (col stats).
__launch_bounds__(256, 2)
__global__ void contrast_kernel(const unsigned short* __restrict__ Eb,
                                const int* __restrict__ cat,
                                float* __restrict__ posPart,
                                float* __restrict__ negPart) {
  __shared__ __align__(16) unsigned short As[TM * DK];  // 64 KB, [row][k] swizzled
  __shared__ __align__(16) unsigned short Bs[TM * 64];  // 16 KB, [col][k-chunk] swizzled

  const int tid = threadIdx.x;
  const int lane = tid & 63;
  const int wv = tid >> 6;
  const int wm = wv >> 1;      // wave row (0..1)
  const int wn = wv & 1;       // wave col (0..1)
  const int quad = lane >> 4;
  const int l16 = lane & 15;
  const int sw = l16 & 7;      // per-lane swizzle key (row&7 == l16&7)

  const int I = blockIdx.x;
  const int dg = (blockIdx.y == 0) ? 8 : (int)blockIdx.y - 1;  // light blocks first
  if (dg == 8 && I >= 32) return;      // d=32 tiles exist only for I<32
  const int ntiles = (dg == 8) ? 1 : 4;
  const int rowBase = I * TM;

  // ---- stage A tile: 64 KB, swizzled source ----
  {
    const char* gbase = (const char*)(Eb + (size_t)rowBase * DK);
#pragma unroll
    for (int i = 0; i < 16; ++i) {
      const int chunk = tid + i * 256;   // LDS 16B-chunk index (lane-contiguous)
      const int row = chunk >> 5;        // 32 chunks per 512B row
      const int c = chunk & 31;
      async_copy16((char*)As + chunk * 16,
                   gbase + row * 512 + (c ^ (row & 7)) * 16);
    }
  }

  // Rows owned by this lane (C layout: col=lane&15, row=quad*4+reg):
  int catRow[16];
  float posmx[16], negsm[16];
#pragma unroll
  for (int ti = 0; ti < 4; ++ti)
#pragma unroll
    for (int r = 0; r < 4; ++r) {
      const int si = ti * 4 + r;
      catRow[si] = cat[rowBase + wm * 64 + ti * 16 + quad * 4 + r];
      posmx[si] = -1e30f;
      negsm[si] = 0.0f;
    }

#pragma unroll 1
  for (int t = 0; t < ntiles; ++t) {
    const int d = (dg == 8) ? 32 : dg * 4 + t;   // block-distance of this tile
    const int colBase = ((I + d) & 63) * TM;

    f32x4 acc[4][4];
#pragma unroll
    for (int ti = 0; ti < 4; ++ti)
#pragma unroll
      for (int tj = 0; tj < 4; ++tj)
        acc[ti][tj] = f32x4{0.f, 0.f, 0.f, 0.f};

#pragma unroll 1
    for (int kc = 0; kc < 4; ++kc) {
      __syncthreads();  // prev Bs consumers done (first iter: covers A wait too)
      {
        const int col8 = tid >> 3;   // col within tile (+32 per it)
        const int c = tid & 7;       // 16B chunk within 128B k-slab
        const char* g = (const char*)Eb +
                        (size_t)(colBase + col8) * 512 +
                        kc * 128 + ((c ^ (col8 & 7)) * 16);
        char* l = (char*)Bs + tid * 16;
#pragma unroll
        for (int it = 0; it < 4; ++it)   // col8+32: (col8&7) unchanged
          async_copy16(l + it * 4096, g + (size_t)it * 32 * 512);
      }
      __syncthreads();  // Bs ready (barrier drains vmcnt)

#pragma unroll
      for (int s = 0; s < 2; ++s) {
        bf16x8 a[4], b[4];
#pragma unroll
        for (int ti = 0; ti < 4; ++ti)
          a[ti] = *(const bf16x8*)&As[(wm * 64 + ti * 16 + l16) * DK +
                                      (((kc * 8 + s * 4 + quad) ^ sw) << 3)];
#pragma unroll
        for (int tj = 0; tj < 4; ++tj)
          b[tj] = *(const bf16x8*)&Bs[(wn * 64 + tj * 16 + l16) * 64 +
                                      (((s * 4 + quad) ^ sw) << 3)];
#pragma unroll
        for (int ti = 0; ti < 4; ++ti)
#pragma unroll
          for (int tj = 0; tj < 4; ++tj)
            acc[ti][tj] = __builtin_amdgcn_mfma_f32_16x16x32_bf16(a[ti], b[tj], acc[ti][tj], 0, 0, 0);
      }
    }

    // ---- fused epilogue for this 128x128 tile (acc = raw cosines) ----
    int catCol[4];
#pragma unroll
    for (int tj = 0; tj < 4; ++tj) catCol[tj] = cat[colBase + wn * 64 + tj * 16 + l16];

    if (d == 0) {
      // diagonal tile: row stats only; self-exclusion needed; no col stats
#pragma unroll
      for (int ti = 0; ti < 4; ++ti)
#pragma unroll
        for (int r = 0; r < 4; ++r) {
          const int si = ti * 4 + r;
          const int rl = wm * 64 + ti * 16 + quad * 4 + r;   // local row
          float pm = posmx[si];
          float ns = negsm[si];
#pragma unroll
          for (int tj = 0; tj < 4; ++tj) {
            const float v = acc[ti][tj][r];
            const bool same = (catRow[si] == catCol[tj]);
            const bool self = (rl == wn * 64 + tj * 16 + l16);
            const float e = exp2f(__fmaf_rn(v, C2E, -C2E));
            ns += same ? 0.0f : e;
            pm = (same && !self) ? fmaxf(pm, v) : pm;
          }
          posmx[si] = pm;
          negsm[si] = ns;
        }
    } else {
      // off-diagonal: row stats + column stats (no self possible, I != J)
      float cp[4], cn[4];
#pragma unroll
      for (int tj = 0; tj < 4; ++tj) { cp[tj] = -1e30f; cn[tj] = 0.0f; }
#pragma unroll
      for (int ti = 0; ti < 4; ++ti)
#pragma unroll
        for (int r = 0; r < 4; ++r) {
          const int si = ti * 4 + r;
          float pm = posmx[si];
          float ns = negsm[si];
#pragma unroll
          for (int tj = 0; tj < 4; ++tj) {
            const float v = acc[ti][tj][r];
            const bool same = (catRow[si] == catCol[tj]);
            const float e = exp2f(__fmaf_rn(v, C2E, -C2E));
            const float en = same ? 0.0f : e;
            ns += en;
            cn[tj] += en;
            pm = same ? fmaxf(pm, v) : pm;
            cp[tj] = same ? fmaxf(cp[tj], v) : cp[tj];
          }
          posmx[si] = pm;
          negsm[si] = ns;
        }

      // column-stat reduce: quads via shuffle, wm halves via Bs scratch
#pragma unroll
      for (int tj = 0; tj < 4; ++tj) {
        cp[tj] = fmaxf(cp[tj], __shfl_xor(cp[tj], 16));
        cp[tj] = fmaxf(cp[tj], __shfl_xor(cp[tj], 32));
        cn[tj] += __shfl_xor(cn[tj], 16);
        cn[tj] += __shfl_xor(cn[tj], 32);
      }
      float* sred = (float*)Bs;
      __syncthreads();           // all waves done reading Bs for MFMA
      if (wm == 1 && quad == 0) {
#pragma unroll
        for (int tj = 0; tj < 4; ++tj) {
          sred[wn * 64 + tj * 16 + l16] = cp[tj];
          sred[128 + wn * 64 + tj * 16 + l16] = cn[tj];
        }
      }
      __syncthreads();           // scratch visible
      if (wm == 0 && quad == 0) {
#pragma unroll
        for (int tj = 0; tj < 4; ++tj) {
          const int C = colBase + wn * 64 + tj * 16 + l16;   // coalesced over l16
          posPart[(size_t)(8 + d) * BN + C] = fmaxf(cp[tj], sred[wn * 64 + tj * 16 + l16]);
          negPart[(size_t)(8 + d) * BN + C] = cn[tj] + sred[128 + wn * 64 + tj * 16 + l16];
        }
      }
      // next tile's kc=0 first sync protects sred reads before restaging Bs
    }
  }

  // ---- row stats: reduce across the 16 lanes sharing each row (cols split) ----
#pragma unroll
  for (int si = 0; si < 16; ++si) {
    float pm = posmx[si], ns = negsm[si];
#pragma unroll
    for (int m = 1; m < 16; m <<= 1) {
      pm = fmaxf(pm, __shfl_xor(pm, m));
      ns += __shfl_xor(ns, m);
    }
    posmx[si] = pm;
    negsm[si] = ns;
  }

  // ---- combine the wn=0 / wn=1 wave halves via LDS (reuse As) ----
  float* red = (float*)As;  // [0..127]=pos, [128..255]=neg
  __syncthreads();
  if (wn == 1 && l16 == 0) {
#pragma unroll
    for (int si = 0; si < 16; ++si) {
      const int rl = wm * 64 + (si >> 2) * 16 + quad * 4 + (si & 3);
      red[rl] = posmx[si];
      red[128 + rl] = negsm[si];
    }
  }
  __syncthreads();
  if (wn == 0 && l16 == 0) {
#pragma unroll
    for (int si = 0; si < 16; ++si) {
      const int rl = wm * 64 + (si >> 2) * 16 + quad * 4 + (si & 3);
      const float pm = fmaxf(posmx[si], red[rl]);
      const float ns = negsm[si] + red[128 + rl];
      posPart[(size_t)dg * BN + rowBase + rl] = pm;  // raw cosine max
      negPart[(size_t)dg * BN + rowBase + rl] = ns;
    }
  }
}

// ---------------- Kernel 3: per-row loss, accumulate, final division ----------------
// 32 blocks x 256: one thread per row; plane-major partials -> coalesced
// 256-thread loads. Planes 0..7 and 9..39 are fully written; plane 8 (row
// stats of dg==8 blocks) is valid only for rows<4096 and plane 40 (col
// stats of d==32 tiles) only for rows>=4096 -- exactly one per row, read
// conditionally, so NO plane initialization is needed anywhere.
// Last block (atomic ticket) performs the division.
__global__ void finalize_kernel(const float* __restrict__ posPart,
                                const float* __restrict__ negPart,
                                float* __restrict__ accum,
                                float* __restrict__ out) {
  const int tid = threadIdx.x;
  const int row = blockIdx.x * 256 + tid;
  float pm = -1e30f, ns = 0.0f;
#pragma unroll
  for (int g = 0; g < 8; ++g) {
    pm = fmaxf(pm, posPart[(size_t)g * BN + row]);
    ns += negPart[(size_t)g * BN + row];
  }
  {
    const int ge = (row < 4096) ? 8 : 40;
    pm = fmaxf(pm, posPart[(size_t)ge * BN + row]);
    ns += negPart[(size_t)ge * BN + row];
  }
#pragma unroll
  for (int g = 9; g < 40; ++g) {
    pm = fmaxf(pm, posPart[(size_t)g * BN + row]);
    ns += negPart[(size_t)g * BN + row];
  }
  float loss = 0.0f, c = 0.0f;
  if (pm > -1e29f && ns > 0.0f) {   // valid: has positive AND negative
    const float pos = pm * INV_T;
    const float lse = INV_T + logf(expf(pos - INV_T) + ns);
    loss = lse - pos;
    c = 1.0f;
  }
#pragma unroll
  for (int m = 1; m < 64; m <<= 1) {
    loss += __shfl_xor(loss, m);
    c += __shfl_xor(c, m);
  }
  __shared__ float sL[4], sC[4];
  const int wv = tid >> 6, lane = tid & 63;
  if (lane == 0) { sL[wv] = loss; sC[wv] = c; }
  __syncthreads();
  if (tid == 0) {
    atomicAdd(&accum[0], sL[0] + sL[1] + sL[2] + sL[3]);
    atomicAdd(&accum[1], sC[0] + sC[1] + sC[2] + sC[3]);
    __threadfence();
    const unsigned old = atomicAdd((unsigned*)&accum[2], 1u);
    if (old == 31u) {            // last block: totals are visible (fence+ticket)
      const float L = atomicAdd(&accum[0], 0.0f);
      const float C = atomicAdd(&accum[1], 0.0f);
      out[0] = (C > 0.0f) ? L / C : 0.0f;
    }
  }
}

extern "C" void kernel_launch(void* const* d_in, const int* in_sizes, int n_in,
                              void* d_out, int out_size, void* d_ws, size_t ws_size,
                              hipStream_t stream) {
  const float* E = (const float*)d_in[0];
  const int* cat = (const int*)d_in[1];
  // d_in[2] (font_labels) unused by the reference.

  // Workspace: [0,4MB) bf16 normalized embeddings; [NP][BN] partials x2; 12B accum.
  unsigned short* Eb = (unsigned short*)d_ws;
  float* posPart = (float*)((char*)d_ws + (size_t)BN * DK * 2);
  float* negPart = posPart + (size_t)NP * BN;
  float* accum = negPart + (size_t)NP * BN;
  float* out = (float*)d_out;

  hipLaunchKernelGGL(norm_kernel, dim3(BN / 4), dim3(256), 0, stream, E, Eb, accum);
  hipLaunchKernelGGL(contrast_kernel, dim3(BN / TM, 9), dim3(256), 0, stream,
                     Eb, cat, posPart, negPart);
  hipLaunchKernelGGL(finalize_kernel, dim3(BN / 256), dim3(256), 0, stream,
                     posPart, negPart, accum, out);
}